// Round 12
// baseline (526.446 us; speedup 1.0000x reference)
//
#include <hip/hip_runtime.h>
#include <hip/hip_bf16.h>

// LoRAModulatedSchnetInteraction: B=2, A=512, F=128, Rbf=64, R=4
// Strategy:
//  - Fold LoRA into per-batch effective weights: Weff[b] = W + A[b]@B[b]  (prep_weights)
//  - x_i: exact fp32 VALU dense (dense_ssp); final two atomwise layers fused (dense2_ssp)
//  - R12 "wave-solo" core: barrier-free main loop. Evidence: R6-R11 all stall-bound
//    (~60% all-wave idle) from barrier-locked phases; occupancy lever dead
//    (R9/R10/R11). New core: 256 blocks x 1024 thr (1 block/CU). Block preloads
//    ALL weights into LDS (swizzled for conflict-free A-frag ds_read_b128) and
//    compacts 4 (b,i) j-lists (3 barriers total). Then 16 waves run SOLO: each
//    processes 16-row j-chunks end-to-end; inter-layer transpose via wave-PRIVATE
//    4KB LDS slice (same verified swizzle as old hbuf; within-wave lgkmcnt only,
//    no __syncthreads). One end barrier + deterministic 4-way y reduction.

typedef float        f32x4  __attribute__((ext_vector_type(4)));
typedef unsigned int u32x4  __attribute__((ext_vector_type(4)));
typedef unsigned int u32x2  __attribute__((ext_vector_type(2)));
typedef __bf16       bf16x8 __attribute__((ext_vector_type(8)));

#define LOG2E 1.44269504089f
#define LN2   0.69314718056f

// h' = ssp(acc+b)/ln2 = log2(2^(acc*log2e + b*log2e - 1) + 0.5)
// bpre = b*log2e - 1. Consumers absorb the ln2 (next-layer weights / s-scale).
__device__ __forceinline__ float ssp_pre(float acc, float bpre) {
  float t = __builtin_amdgcn_exp2f(__builtin_fmaf(acc, LOG2E, bpre));
  return __builtin_amdgcn_logf(t + 0.5f);
}

__device__ __forceinline__ float ssp_f(float v) {
  float t = __builtin_amdgcn_exp2f(v * LOG2E);
  return LN2 * __builtin_amdgcn_logf(__builtin_fmaf(t, 0.5f, 0.5f));
}

__device__ __forceinline__ unsigned short f2bfu(float f) {
  __hip_bfloat16 h = __float2bfloat16(f);
  return __builtin_bit_cast(unsigned short, h);
}

__device__ __forceinline__ u32x4 pack8(f32x4 a, f32x4 b) {
  u32x4 u;
  u.x = (unsigned)f2bfu(a.x) | ((unsigned)f2bfu(a.y) << 16);
  u.y = (unsigned)f2bfu(a.z) | ((unsigned)f2bfu(a.w) << 16);
  u.z = (unsigned)f2bfu(b.x) | ((unsigned)f2bfu(b.y) << 16);
  u.w = (unsigned)f2bfu(b.z) | ((unsigned)f2bfu(b.w) << 16);
  return u;
}

__device__ __forceinline__ f32x4 fzero4() { f32x4 z = {0.f, 0.f, 0.f, 0.f}; return z; }

// ---------------------------------------------------------------------------
// Weight prep: Weff[b] = W + A[b] @ B[b].
// Filter layers (l=1,2,3) stored TRANSPOSED bf16 [b][nout][din]; l=2,3 pre-scaled
// by ln2 (ssp log2-form folding). bc/a0/a1 stored fp32 [b][k][n].
// ---------------------------------------------------------------------------
__global__ void prep_weights(
    const float* __restrict__ W_bc, const float* __restrict__ A_bc, const float* __restrict__ B_bc,
    const float* __restrict__ W_f0, const float* __restrict__ A_f0, const float* __restrict__ B_f0,
    const float* __restrict__ W_f1, const float* __restrict__ A_f1, const float* __restrict__ B_f1,
    const float* __restrict__ W_f2, const float* __restrict__ A_f2, const float* __restrict__ B_f2,
    const float* __restrict__ W_a0, const float* __restrict__ A_a0, const float* __restrict__ B_a0,
    const float* __restrict__ W_a1, const float* __restrict__ A_a1, const float* __restrict__ B_a1,
    unsigned short* __restrict__ Wt0, unsigned short* __restrict__ Wt1, unsigned short* __restrict__ Wt2,
    float* __restrict__ Wbc, float* __restrict__ Wa0, float* __restrict__ Wa1)
{
  const int l = blockIdx.y, b = blockIdx.z;
  const int e = blockIdx.x * 256 + threadIdx.x;
  const float *W, *A, *Bm; int din;
  switch (l) {
    case 0:  W = W_bc; A = A_bc; Bm = B_bc; din = 128; break;
    case 1:  W = W_f0; A = A_f0; Bm = B_f0; din = 64;  break;
    case 2:  W = W_f1; A = A_f1; Bm = B_f1; din = 128; break;
    case 3:  W = W_f2; A = A_f2; Bm = B_f2; din = 128; break;
    case 4:  W = W_a0; A = A_a0; Bm = B_a0; din = 128; break;
    default: W = W_a1; A = A_a1; Bm = B_a1; din = 128; break;
  }
  if (e >= din * 128) return;
  const int k = e >> 7, n = e & 127;
  float wv = W[k * 128 + n];
  #pragma unroll
  for (int r = 0; r < 4; ++r)
    wv += A[(b * din + k) * 4 + r] * Bm[(b * 4 + r) * 128 + n];
  if (l == 1)      Wt0[(b * 128 + n) * 64  + k] = f2bfu(wv);
  else if (l == 2) Wt1[(b * 128 + n) * 128 + k] = f2bfu(wv * LN2);
  else if (l == 3) Wt2[(b * 128 + n) * 128 + k] = f2bfu(wv * LN2);
  else if (l == 0) Wbc[(b * 128 + k) * 128 + n] = wv;
  else if (l == 4) Wa0[(b * 128 + k) * 128 + n] = wv;
  else             Wa1[(b * 128 + k) * 128 + n] = wv;
}

// ---------------------------------------------------------------------------
// dense_ssp: out[row,n] = ssp(sum_k in[row,k]*W[b,k,n] + bias[n])
// ---------------------------------------------------------------------------
__global__ __launch_bounds__(512) void dense_ssp(
    const float* __restrict__ in, const float* __restrict__ W,
    const float* __restrict__ bias, float* __restrict__ out)
{
  __shared__ float in_l[4][128];
  const int t = threadIdx.x;
  const int rg0 = blockIdx.x << 2;
  const int b = rg0 >> 9;
  in_l[t >> 7][t & 127] = in[rg0 * 128 + t];
  __syncthreads();
  const int j = t >> 7, n = t & 127;
  const float* wp = W + (b << 14) + n;
  const float* ip = in_l[j];
  float acc = 0.f;
  #pragma unroll 8
  for (int k = 0; k < 128; ++k) acc += ip[k] * wp[k << 7];
  out[(rg0 + j) * 128 + n] = ssp_f(acc + bias[n]);
}

// ---------------------------------------------------------------------------
// dense2_ssp: fused final two atomwise layers.
// h = ssp(in @ W0 + b0); out = ssp(h @ W1 + b1) + resid
// ---------------------------------------------------------------------------
__global__ __launch_bounds__(512) void dense2_ssp(
    const float* __restrict__ in,
    const float* __restrict__ W0, const float* __restrict__ b0,
    const float* __restrict__ W1, const float* __restrict__ b1,
    const float* __restrict__ resid, float* __restrict__ out)
{
  __shared__ float in_l[4][128];
  __shared__ float h_l[4][128];
  const int t = threadIdx.x;
  const int rg0 = blockIdx.x << 2;
  const int b = rg0 >> 9;
  in_l[t >> 7][t & 127] = in[rg0 * 128 + t];
  __syncthreads();
  const int j = t >> 7, n = t & 127;
  {
    const float* wp = W0 + (b << 14) + n;
    const float* ip = in_l[j];
    float acc = 0.f;
    #pragma unroll 8
    for (int k = 0; k < 128; ++k) acc += ip[k] * wp[k << 7];
    h_l[j][n] = ssp_f(acc + b0[n]);
  }
  __syncthreads();
  {
    const float* wp = W1 + (b << 14) + n;
    const float* ip = h_l[j];
    float acc = 0.f;
    #pragma unroll 8
    for (int k = 0; k < 128; ++k) acc += ip[k] * wp[k << 7];
    const int oi = (rg0 + j) * 128 + n;
    out[oi] = ssp_f(acc + b1[n]) + resid[oi];
  }
}

// ---------------------------------------------------------------------------
// ssp4 + pack helper
// ---------------------------------------------------------------------------
__device__ __forceinline__ u32x2 ssp4_pack(f32x4 a, f32x4 bp) {
  float e0 = ssp_pre(a.x, bp.x);
  float e1 = ssp_pre(a.y, bp.y);
  float e2 = ssp_pre(a.z, bp.z);
  float e3 = ssp_pre(a.w, bp.w);
  u32x2 pk;
  pk.x = (unsigned)f2bfu(e0) | ((unsigned)f2bfu(e1) << 16);
  pk.y = (unsigned)f2bfu(e2) | ((unsigned)f2bfu(e3) << 16);
  return pk;
}

// ---------------------------------------------------------------------------
// schnet_core (wave-solo): grid 256 x 1024 threads (1 block/CU, 16 waves).
// Block bg handles bi = bg*4 + q (q=0..3), all same batch b = bg>>7.
// Preamble (3 barriers): stage Wt0/1/2 into LDS swizzled; compact 4 j-lists.
// Main loop: wave w -> q = w&3, chunks c = (w>>2), +4, ... of 16 compacted j's.
//   Per chunk, BARRIER-FREE: f->reg B-frags (coalesced per row) | G1 (A-frags
//   streamed from ws0) | E1 ssp->bf16 -> wave-PRIVATE hT slice (swizzled) |
//   G2 (ws1, B from hT) | E2 -> hT | G3 (ws2) | E3: accy += s * xi * h3'.
//   A-frag/B reads use the verified 16B-slot XOR swizzle (conflict-free).
// End: 1 barrier, deterministic 4-wave y reduction per (b,i) via LDS.
// ---------------------------------------------------------------------------
__global__ __launch_bounds__(1024) void schnet_core(
    const float* __restrict__ f_ij, const float* __restrict__ c_ij,
    const int* __restrict__ mask,
    const unsigned short* __restrict__ Wt0, const unsigned short* __restrict__ Wt1,
    const unsigned short* __restrict__ Wt2,
    const float* __restrict__ bias0, const float* __restrict__ bias1,
    const float* __restrict__ bias2,
    const float* __restrict__ xi, float* __restrict__ y)
{
  __shared__ __align__(16) unsigned short ws0[128 * 64];    // Wt0[b], swizzled rows (128B)
  __shared__ __align__(16) unsigned short ws1[128 * 128];   // Wt1[b], swizzled rows (256B)
  __shared__ __align__(16) unsigned short ws2[128 * 128];   // Wt2[b], swizzled rows (256B)
  __shared__ __align__(16) unsigned short hT[16 * 2048];    // 16 waves x (16 rows x 256B)
  __shared__ int   jl[4][512];
  __shared__ float bias_l[384];                             // 3x128: b*log2e - 1
  __shared__ int cnt_s[4][8], base_s[4][8], na_s[4];

  const int tid  = threadIdx.x;
  const int lane = tid & 63;
  const int w    = tid >> 6;            // wave 0..15
  const int lrow = lane & 15;
  const int lgrp = lane >> 4;
  const int bg   = blockIdx.x;          // 0..255
  const int b    = bg >> 7;
  const int bi0  = bg << 2;

  // ---- stage biases, init jlist, stage weights (swizzled) ----
  if (tid < 384) {
    const float* bp = (tid < 128) ? bias0 : (tid < 256) ? bias1 : bias2;
    bias_l[tid] = __builtin_fmaf(bp[tid & 127], LOG2E, -1.0f);
  }
  ((int*)jl)[tid] = 0;
  ((int*)jl)[tid + 1024] = 0;
  {
    // ws0: 1024 x 16B slots; row n (128B) slot c; swz ^((n&7)<<4)
    const int n = tid >> 3, c = tid & 7;
    *(u32x4*)((char*)ws0 + n * 128 + ((c * 16) ^ ((n & 7) << 4))) =
        *(const u32x4*)(Wt0 + (b << 13) + n * 64 + c * 8);
  }
  #pragma unroll
  for (int pp = 0; pp < 2; ++pp) {
    // ws1/ws2: 2048 x 16B slots each; row n (256B) slot c; swz ^((n&15)<<4)
    const int s = tid + (pp << 10);
    const int n = s >> 4, c = s & 15;
    const int dst = n * 256 + ((c * 16) ^ ((n & 15) << 4));
    *(u32x4*)((char*)ws1 + dst) = *(const u32x4*)(Wt1 + (b << 14) + n * 128 + c * 8);
    *(u32x4*)((char*)ws2 + dst) = *(const u32x4*)(Wt2 + (b << 14) + n * 128 + c * 8);
  }

  // ---- deterministic compaction: passes A (q=0,1) and B (q=2,3) ----
  const int qA = tid >> 9;              // 0 or 1
  const int jj = tid & 511;
  const int mA = mask[((bi0 + qA) << 9) + jj];
  const int mB = mask[((bi0 + 2 + qA) << 9) + jj];
  unsigned long long balA = __ballot(mA != 0);
  unsigned long long balB = __ballot(mB != 0);
  if (lane == 0) {
    cnt_s[qA][w & 7]     = __popcll(balA);
    cnt_s[2 + qA][w & 7] = __popcll(balB);
  }
  __syncthreads();
  if (tid < 4) {
    int s = 0;
    for (int cc = 0; cc < 8; ++cc) { base_s[tid][cc] = s; s += cnt_s[tid][cc]; }
    na_s[tid] = s;
  }
  __syncthreads();
  const unsigned long long lm = (1ull << lane) - 1ull;
  if (mA) jl[qA][base_s[qA][w & 7] + __popcll(balA & lm)] = jj;
  if (mB) jl[2 + qA][base_s[2 + qA][w & 7] + __popcll(balB & lm)] = jj;
  __syncthreads();                      // last block barrier before solo phase

  // ---- per-wave solo main loop ----
  const int q   = w & 3;
  const int k4  = w >> 2;               // 0..3
  const int bi  = bi0 + q;
  const int mb  = bi << 9;
  const float* fbase = f_ij + ((size_t)mb << 6);
  const float* cb    = c_ij + mb;
  const int na  = na_s[q];
  const int nch = (na + 15) >> 4;
  char* myh = (char*)hT + (w << 12);    // private 4KB: 16 rows x 256B
  const int swj = lrow << 4;            // my j-row swizzle (row = lane&15)

  f32x4 accy[8];
  #pragma unroll
  for (int nt = 0; nt < 8; ++nt) accy[nt] = fzero4();

  for (int c = k4; c < nch; c += 4) {
    const int ridx = (c << 4) + lrow;
    const int ja   = jl[q][ridx];       // 0 for padded tail (valid memory)
    const float sval = (ridx < na) ? cb[ja] * LN2 : 0.f;
    const float* xr = xi + ((size_t)((b << 9) + ja) << 7);

    // ---- f -> B-frags (lane's own j-row; coalesced across lgrp) ----
    bf16x8 fb[2];
    #pragma unroll
    for (int ks = 0; ks < 2; ++ks) {
      const float* fp = fbase + ja * 64 + ks * 32 + lgrp * 8;
      f32x4 v0 = *(const f32x4*)fp;
      f32x4 v1 = *(const f32x4*)(fp + 4);
      u32x4 pk = pack8(v0, v1);
      fb[ks] = __builtin_bit_cast(bf16x8, pk);
    }

    f32x4 acc[8];

    // ---- G1: h1[n, j] = Wt0 * f^T (K=64), A streamed from ws0 ----
    #pragma unroll
    for (int nt = 0; nt < 8; ++nt) acc[nt] = fzero4();
    #pragma unroll
    for (int nt = 0; nt < 8; ++nt) {
      const int n = nt * 16 + lrow;
      const char* ap = (const char*)ws0 + n * 128;
      const int sw = (n & 7) << 4;
      #pragma unroll
      for (int ks = 0; ks < 2; ++ks) {
        bf16x8 af = *(const bf16x8*)(ap + ((lgrp * 16 + ks * 64) ^ sw));
        acc[nt] = __builtin_amdgcn_mfma_f32_16x16x32_bf16(af, fb[ks], acc[nt], 0, 0, 0);
      }
    }

    // ---- E1: ssp -> bf16 -> private hT (row = my j = lrow) ----
    {
      char* hr = myh + lrow * 256;
      #pragma unroll
      for (int nt = 0; nt < 8; ++nt) {
        f32x4 bp = *(const f32x4*)(bias_l + nt * 16 + lgrp * 4);
        u32x2 pk = ssp4_pack(acc[nt], bp);
        *(u32x2*)(hr + ((nt * 32 + lgrp * 8) ^ swj)) = pk;
      }
    }

    // ---- G2: h2 = Wt1' * h1'^T (K=128) ----
    {
      bf16x8 hb[4];
      const char* hr = myh + lrow * 256;
      #pragma unroll
      for (int kt = 0; kt < 4; ++kt)
        hb[kt] = *(const bf16x8*)(hr + ((lgrp * 16 + kt * 64) ^ swj));
      #pragma unroll
      for (int nt = 0; nt < 8; ++nt) acc[nt] = fzero4();
      #pragma unroll
      for (int nt = 0; nt < 8; ++nt) {
        const int n = nt * 16 + lrow;
        const char* ap = (const char*)ws1 + n * 256;
        const int sw = (n & 15) << 4;
        #pragma unroll
        for (int kt = 0; kt < 4; ++kt) {
          bf16x8 af = *(const bf16x8*)(ap + ((lgrp * 16 + kt * 64) ^ sw));
          acc[nt] = __builtin_amdgcn_mfma_f32_16x16x32_bf16(af, hb[kt], acc[nt], 0, 0, 0);
        }
      }
    }

    // ---- E2: ssp -> bf16 -> private hT (overwrite; within-wave order) ----
    {
      char* hr = myh + lrow * 256;
      #pragma unroll
      for (int nt = 0; nt < 8; ++nt) {
        f32x4 bp = *(const f32x4*)(bias_l + 128 + nt * 16 + lgrp * 4);
        u32x2 pk = ssp4_pack(acc[nt], bp);
        *(u32x2*)(hr + ((nt * 32 + lgrp * 8) ^ swj)) = pk;
      }
    }

    // ---- G3: h3 = Wt2' * h2'^T (K=128) ----
    {
      bf16x8 hb[4];
      const char* hr = myh + lrow * 256;
      #pragma unroll
      for (int kt = 0; kt < 4; ++kt)
        hb[kt] = *(const bf16x8*)(hr + ((lgrp * 16 + kt * 64) ^ swj));
      #pragma unroll
      for (int nt = 0; nt < 8; ++nt) acc[nt] = fzero4();
      #pragma unroll
      for (int nt = 0; nt < 8; ++nt) {
        const int n = nt * 16 + lrow;
        const char* ap = (const char*)ws2 + n * 256;
        const int sw = (n & 15) << 4;
        #pragma unroll
        for (int kt = 0; kt < 4; ++kt) {
          bf16x8 af = *(const bf16x8*)(ap + ((lgrp * 16 + kt * 64) ^ sw));
          acc[nt] = __builtin_amdgcn_mfma_f32_16x16x32_bf16(af, hb[kt], acc[nt], 0, 0, 0);
        }
      }
    }

    // ---- E3: accy += s * xi[ja, n] * h3' ----
    #pragma unroll
    for (int nt = 0; nt < 8; ++nt) {
      f32x4 bp = *(const f32x4*)(bias_l + 256 + nt * 16 + lgrp * 4);
      f32x4 xv = *(const f32x4*)(xr + nt * 16 + lgrp * 4);
      float h0 = ssp_pre(acc[nt].x, bp.x);
      float h1 = ssp_pre(acc[nt].y, bp.y);
      float h2 = ssp_pre(acc[nt].z, bp.z);
      float h3 = ssp_pre(acc[nt].w, bp.w);
      accy[nt].x += sval * xv.x * h0;
      accy[nt].y += sval * xv.y * h1;
      accy[nt].z += sval * xv.z * h2;
      accy[nt].w += sval * xv.w * h3;
    }
  }

  // ---- reduce over 16 j-lanes (within lgrp-preserving groups) ----
  #pragma unroll
  for (int d = 1; d < 16; d <<= 1) {
    #pragma unroll
    for (int nt = 0; nt < 8; ++nt) {
      accy[nt].x += __shfl_xor(accy[nt].x, d, 64);
      accy[nt].y += __shfl_xor(accy[nt].y, d, 64);
      accy[nt].z += __shfl_xor(accy[nt].z, d, 64);
      accy[nt].w += __shfl_xor(accy[nt].w, d, 64);
    }
  }
  __syncthreads();                      // all waves done; hT reusable
  float* yred = (float*)hT;             // [16 waves][128]
  if (lrow == 0) {
    #pragma unroll
    for (int nt = 0; nt < 8; ++nt)
      *(f32x4*)(yred + (w << 7) + nt * 16 + lgrp * 4) = accy[nt];
  }
  __syncthreads();
  if (tid < 512) {
    const int q2 = tid >> 7, n = tid & 127;
    float s = yred[((q2)      << 7) + n]
            + yred[((4 + q2)  << 7) + n]
            + yred[((8 + q2)  << 7) + n]
            + yred[((12 + q2) << 7) + n];
    y[((bi0 + q2) << 7) + n] = s;
  }
}

// ---------------------------------------------------------------------------
extern "C" void kernel_launch(void* const* d_in, const int* in_sizes, int n_in,
                              void* d_out, int out_size, void* d_ws, size_t ws_size,
                              hipStream_t stream)
{
  const float* x    = (const float*)d_in[0];
  const float* f_ij = (const float*)d_in[1];
  const float* c_ij = (const float*)d_in[2];
  const int*   mask = (const int*)d_in[3];
  const float* W_bc = (const float*)d_in[4];
  const float* b_bc = (const float*)d_in[5];
  const float* A_bc = (const float*)d_in[6];
  const float* B_bc = (const float*)d_in[7];
  const float* W_f0 = (const float*)d_in[8];
  const float* b_f0 = (const float*)d_in[9];
  const float* A_f0 = (const float*)d_in[10];
  const float* B_f0 = (const float*)d_in[11];
  const float* W_f1 = (const float*)d_in[12];
  const float* b_f1 = (const float*)d_in[13];
  const float* A_f1 = (const float*)d_in[14];
  const float* B_f1 = (const float*)d_in[15];
  const float* W_f2 = (const float*)d_in[16];
  const float* b_f2 = (const float*)d_in[17];
  const float* A_f2 = (const float*)d_in[18];
  const float* B_f2 = (const float*)d_in[19];
  const float* W_a0 = (const float*)d_in[20];
  const float* b_a0 = (const float*)d_in[21];
  const float* A_a0 = (const float*)d_in[22];
  const float* B_a0 = (const float*)d_in[23];
  const float* W_a1 = (const float*)d_in[24];
  const float* b_a1 = (const float*)d_in[25];
  const float* A_a1 = (const float*)d_in[26];
  const float* B_a1 = (const float*)d_in[27];
  float* out = (float*)d_out;

  char* ws = (char*)d_ws;
  unsigned short* Wt0 = (unsigned short*)(ws);            //  32768 B
  unsigned short* Wt1 = (unsigned short*)(ws + 32768);    //  65536 B
  unsigned short* Wt2 = (unsigned short*)(ws + 98304);    //  65536 B
  float* Wbc = (float*)(ws + 163840);                     // 131072 B
  float* Wa0 = (float*)(ws + 294912);                     // 131072 B
  float* Wa1 = (float*)(ws + 425984);                     // 131072 B
  float* xi  = (float*)(ws + 557056);                     // 524288 B
  float* yp  = (float*)(ws + 1081344);                    // 524288 B (~1.6 MB total)

  prep_weights<<<dim3(64, 6, 2), 256, 0, stream>>>(
      W_bc, A_bc, B_bc, W_f0, A_f0, B_f0, W_f1, A_f1, B_f1,
      W_f2, A_f2, B_f2, W_a0, A_a0, B_a0, W_a1, A_a1, B_a1,
      Wt0, Wt1, Wt2, Wbc, Wa0, Wa1);

  dense_ssp<<<256, 512, 0, stream>>>(x, Wbc, b_bc, xi);

  schnet_core<<<256, 1024, 0, stream>>>(f_ij, c_ij, mask, Wt0, Wt1, Wt2,
                                        b_f0, b_f1, b_f2, xi, yp);

  dense2_ssp<<<256, 512, 0, stream>>>(yp, Wa0, b_a0, Wa1, b_a1, x, out);
}

// Round 13
// 365.913 us; speedup vs baseline: 1.4387x; 1.4387x over previous
//
#include <hip/hip_runtime.h>
#include <hip/hip_bf16.h>

// LoRAModulatedSchnetInteraction: B=2, A=512, F=128, Rbf=64, R=4
// Strategy:
//  - Fold LoRA into per-batch effective weights: Weff[b] = W + A[b]@B[b]  (prep_weights)
//  - x_i: exact fp32 VALU dense (dense_ssp); final two atomwise layers fused (dense2_ssp)
//  - R13 wave-solo core at the RIGHT thread count. R12 (1024 thr) verified the
//    barrier-free structure numerically but launch_bounds(1024) caps VGPR at 64
//    -> ~100-reg live state spilled (428MB scratch writes, 526us). R13: 512 thr
//    = 8 waves, launch_bounds(512,1) -> VGPR budget 256, no spill possible.
//    LDS ~124KB (ws weights 80K + hT 32K + jl 8K) -> 1 block/CU, grid 256,
//    2 waves per (b,i) list. Main loop has ZERO barriers: each wave processes
//    16-row j-chunks end-to-end (f->regs | G1 | E1->private hT | G2 | E2 | G3 |
//    E3 accumulate), weights streamed from shared read-only LDS (swizzled,
//    conflict-free), inter-layer transpose via wave-private hT slice ordered by
//    within-wave lgkmcnt. One end barrier + deterministic 2-way y reduction.

typedef float        f32x4  __attribute__((ext_vector_type(4)));
typedef unsigned int u32x4  __attribute__((ext_vector_type(4)));
typedef unsigned int u32x2  __attribute__((ext_vector_type(2)));
typedef __bf16       bf16x8 __attribute__((ext_vector_type(8)));

#define LOG2E 1.44269504089f
#define LN2   0.69314718056f

// h' = ssp(acc+b)/ln2 = log2(2^(acc*log2e + b*log2e - 1) + 0.5)
// bpre = b*log2e - 1. Consumers absorb the ln2 (next-layer weights / s-scale).
__device__ __forceinline__ float ssp_pre(float acc, float bpre) {
  float t = __builtin_amdgcn_exp2f(__builtin_fmaf(acc, LOG2E, bpre));
  return __builtin_amdgcn_logf(t + 0.5f);
}

__device__ __forceinline__ float ssp_f(float v) {
  float t = __builtin_amdgcn_exp2f(v * LOG2E);
  return LN2 * __builtin_amdgcn_logf(__builtin_fmaf(t, 0.5f, 0.5f));
}

__device__ __forceinline__ unsigned short f2bfu(float f) {
  __hip_bfloat16 h = __float2bfloat16(f);
  return __builtin_bit_cast(unsigned short, h);
}

__device__ __forceinline__ u32x4 pack8(f32x4 a, f32x4 b) {
  u32x4 u;
  u.x = (unsigned)f2bfu(a.x) | ((unsigned)f2bfu(a.y) << 16);
  u.y = (unsigned)f2bfu(a.z) | ((unsigned)f2bfu(a.w) << 16);
  u.z = (unsigned)f2bfu(b.x) | ((unsigned)f2bfu(b.y) << 16);
  u.w = (unsigned)f2bfu(b.z) | ((unsigned)f2bfu(b.w) << 16);
  return u;
}

__device__ __forceinline__ f32x4 fzero4() { f32x4 z = {0.f, 0.f, 0.f, 0.f}; return z; }

// ---------------------------------------------------------------------------
// Weight prep: Weff[b] = W + A[b] @ B[b].
// Filter layers (l=1,2,3) stored TRANSPOSED bf16 [b][nout][din]; l=2,3 pre-scaled
// by ln2 (ssp log2-form folding). bc/a0/a1 stored fp32 [b][k][n].
// ---------------------------------------------------------------------------
__global__ void prep_weights(
    const float* __restrict__ W_bc, const float* __restrict__ A_bc, const float* __restrict__ B_bc,
    const float* __restrict__ W_f0, const float* __restrict__ A_f0, const float* __restrict__ B_f0,
    const float* __restrict__ W_f1, const float* __restrict__ A_f1, const float* __restrict__ B_f1,
    const float* __restrict__ W_f2, const float* __restrict__ A_f2, const float* __restrict__ B_f2,
    const float* __restrict__ W_a0, const float* __restrict__ A_a0, const float* __restrict__ B_a0,
    const float* __restrict__ W_a1, const float* __restrict__ A_a1, const float* __restrict__ B_a1,
    unsigned short* __restrict__ Wt0, unsigned short* __restrict__ Wt1, unsigned short* __restrict__ Wt2,
    float* __restrict__ Wbc, float* __restrict__ Wa0, float* __restrict__ Wa1)
{
  const int l = blockIdx.y, b = blockIdx.z;
  const int e = blockIdx.x * 256 + threadIdx.x;
  const float *W, *A, *Bm; int din;
  switch (l) {
    case 0:  W = W_bc; A = A_bc; Bm = B_bc; din = 128; break;
    case 1:  W = W_f0; A = A_f0; Bm = B_f0; din = 64;  break;
    case 2:  W = W_f1; A = A_f1; Bm = B_f1; din = 128; break;
    case 3:  W = W_f2; A = A_f2; Bm = B_f2; din = 128; break;
    case 4:  W = W_a0; A = A_a0; Bm = B_a0; din = 128; break;
    default: W = W_a1; A = A_a1; Bm = B_a1; din = 128; break;
  }
  if (e >= din * 128) return;
  const int k = e >> 7, n = e & 127;
  float wv = W[k * 128 + n];
  #pragma unroll
  for (int r = 0; r < 4; ++r)
    wv += A[(b * din + k) * 4 + r] * Bm[(b * 4 + r) * 128 + n];
  if (l == 1)      Wt0[(b * 128 + n) * 64  + k] = f2bfu(wv);
  else if (l == 2) Wt1[(b * 128 + n) * 128 + k] = f2bfu(wv * LN2);
  else if (l == 3) Wt2[(b * 128 + n) * 128 + k] = f2bfu(wv * LN2);
  else if (l == 0) Wbc[(b * 128 + k) * 128 + n] = wv;
  else if (l == 4) Wa0[(b * 128 + k) * 128 + n] = wv;
  else             Wa1[(b * 128 + k) * 128 + n] = wv;
}

// ---------------------------------------------------------------------------
// dense_ssp: out[row,n] = ssp(sum_k in[row,k]*W[b,k,n] + bias[n])
// ---------------------------------------------------------------------------
__global__ __launch_bounds__(512) void dense_ssp(
    const float* __restrict__ in, const float* __restrict__ W,
    const float* __restrict__ bias, float* __restrict__ out)
{
  __shared__ float in_l[4][128];
  const int t = threadIdx.x;
  const int rg0 = blockIdx.x << 2;
  const int b = rg0 >> 9;
  in_l[t >> 7][t & 127] = in[rg0 * 128 + t];
  __syncthreads();
  const int j = t >> 7, n = t & 127;
  const float* wp = W + (b << 14) + n;
  const float* ip = in_l[j];
  float acc = 0.f;
  #pragma unroll 8
  for (int k = 0; k < 128; ++k) acc += ip[k] * wp[k << 7];
  out[(rg0 + j) * 128 + n] = ssp_f(acc + bias[n]);
}

// ---------------------------------------------------------------------------
// dense2_ssp: fused final two atomwise layers.
// h = ssp(in @ W0 + b0); out = ssp(h @ W1 + b1) + resid
// ---------------------------------------------------------------------------
__global__ __launch_bounds__(512) void dense2_ssp(
    const float* __restrict__ in,
    const float* __restrict__ W0, const float* __restrict__ b0,
    const float* __restrict__ W1, const float* __restrict__ b1,
    const float* __restrict__ resid, float* __restrict__ out)
{
  __shared__ float in_l[4][128];
  __shared__ float h_l[4][128];
  const int t = threadIdx.x;
  const int rg0 = blockIdx.x << 2;
  const int b = rg0 >> 9;
  in_l[t >> 7][t & 127] = in[rg0 * 128 + t];
  __syncthreads();
  const int j = t >> 7, n = t & 127;
  {
    const float* wp = W0 + (b << 14) + n;
    const float* ip = in_l[j];
    float acc = 0.f;
    #pragma unroll 8
    for (int k = 0; k < 128; ++k) acc += ip[k] * wp[k << 7];
    h_l[j][n] = ssp_f(acc + b0[n]);
  }
  __syncthreads();
  {
    const float* wp = W1 + (b << 14) + n;
    const float* ip = h_l[j];
    float acc = 0.f;
    #pragma unroll 8
    for (int k = 0; k < 128; ++k) acc += ip[k] * wp[k << 7];
    const int oi = (rg0 + j) * 128 + n;
    out[oi] = ssp_f(acc + b1[n]) + resid[oi];
  }
}

// ---------------------------------------------------------------------------
// ssp4 + pack helper
// ---------------------------------------------------------------------------
__device__ __forceinline__ u32x2 ssp4_pack(f32x4 a, f32x4 bp) {
  float e0 = ssp_pre(a.x, bp.x);
  float e1 = ssp_pre(a.y, bp.y);
  float e2 = ssp_pre(a.z, bp.z);
  float e3 = ssp_pre(a.w, bp.w);
  u32x2 pk;
  pk.x = (unsigned)f2bfu(e0) | ((unsigned)f2bfu(e1) << 16);
  pk.y = (unsigned)f2bfu(e2) | ((unsigned)f2bfu(e3) << 16);
  return pk;
}

// ---------------------------------------------------------------------------
// schnet_core (wave-solo, 512 thr): grid 256 x 512 (1 block/CU, 8 waves).
// Block bg handles bi = bg*4 + q (q=0..3), all same batch b = bg>>7.
// Preamble (3 barriers): stage Wt0/1/2 into LDS swizzled; compact 4 j-lists.
// Main loop: wave w -> q = w&3, chunks c = (w>>2), +2, ... of 16 compacted j's.
//   Per chunk, BARRIER-FREE: f->reg B-frags | G1 (A-frags streamed from ws0) |
//   E1 ssp->bf16 -> wave-PRIVATE hT slice (swizzled) | G2 (ws1) | E2 -> hT |
//   G3 (ws2) | E3: accy += s * xi * h3'. Within-wave lgkmcnt orders hT.
// End: 1 barrier, deterministic 2-wave y reduction per (b,i) via LDS.
// ---------------------------------------------------------------------------
__global__ __launch_bounds__(512, 1) void schnet_core(
    const float* __restrict__ f_ij, const float* __restrict__ c_ij,
    const int* __restrict__ mask,
    const unsigned short* __restrict__ Wt0, const unsigned short* __restrict__ Wt1,
    const unsigned short* __restrict__ Wt2,
    const float* __restrict__ bias0, const float* __restrict__ bias1,
    const float* __restrict__ bias2,
    const float* __restrict__ xi, float* __restrict__ y)
{
  __shared__ __align__(16) unsigned short ws0[128 * 64];    // Wt0[b], swizzled rows (128B)
  __shared__ __align__(16) unsigned short ws1[128 * 128];   // Wt1[b], swizzled rows (256B)
  __shared__ __align__(16) unsigned short ws2[128 * 128];   // Wt2[b], swizzled rows (256B)
  __shared__ __align__(16) unsigned short hT[8 * 2048];     // 8 waves x (16 rows x 256B)
  __shared__ int   jl[4][512];
  __shared__ float bias_l[384];                             // 3x128: b*log2e - 1
  __shared__ int cnt_s[4][8], base_s[4][8], na_s[4];

  const int tid  = threadIdx.x;
  const int lane = tid & 63;
  const int w    = tid >> 6;            // wave 0..7
  const int lrow = lane & 15;
  const int lgrp = lane >> 4;
  const int bg   = blockIdx.x;          // 0..255
  const int b    = bg >> 7;
  const int bi0  = bg << 2;

  // ---- stage biases, init jlist, stage weights (swizzled) ----
  if (tid < 384) {
    const float* bp = (tid < 128) ? bias0 : (tid < 256) ? bias1 : bias2;
    bias_l[tid] = __builtin_fmaf(bp[tid & 127], LOG2E, -1.0f);
  }
  #pragma unroll
  for (int s = 0; s < 4; ++s) ((int*)jl)[tid + (s << 9)] = 0;
  #pragma unroll
  for (int pp = 0; pp < 2; ++pp) {
    // ws0: 1024 x 16B slots; row n (128B) slot c; swz ^((n&7)<<4)
    const int s = tid + (pp << 9);
    const int n = s >> 3, c = s & 7;
    *(u32x4*)((char*)ws0 + n * 128 + ((c * 16) ^ ((n & 7) << 4))) =
        *(const u32x4*)(Wt0 + (b << 13) + n * 64 + c * 8);
  }
  #pragma unroll
  for (int pp = 0; pp < 4; ++pp) {
    // ws1/ws2: 2048 x 16B slots each; row n (256B) slot c; swz ^((n&15)<<4)
    const int s = tid + (pp << 9);
    const int n = s >> 4, c = s & 15;
    const int dst = n * 256 + ((c * 16) ^ ((n & 15) << 4));
    *(u32x4*)((char*)ws1 + dst) = *(const u32x4*)(Wt1 + (b << 14) + n * 128 + c * 8);
    *(u32x4*)((char*)ws2 + dst) = *(const u32x4*)(Wt2 + (b << 14) + n * 128 + c * 8);
  }

  // ---- deterministic compaction: 4 sequential full-block ballot passes ----
  unsigned long long balp[4];
  #pragma unroll
  for (int p = 0; p < 4; ++p) {
    const int m = mask[((bi0 + p) << 9) + tid];
    balp[p] = __ballot(m != 0);
    if (lane == 0) cnt_s[p][w] = __popcll(balp[p]);
  }
  __syncthreads();
  if (tid < 4) {
    int s = 0;
    for (int cc = 0; cc < 8; ++cc) { base_s[tid][cc] = s; s += cnt_s[tid][cc]; }
    na_s[tid] = s;
  }
  __syncthreads();
  const unsigned long long lm = (1ull << lane) - 1ull;
  #pragma unroll
  for (int p = 0; p < 4; ++p) {
    if ((balp[p] >> lane) & 1ull)
      jl[p][base_s[p][w] + __popcll(balp[p] & lm)] = tid;
  }
  __syncthreads();                      // last block barrier before solo phase

  // ---- per-wave solo main loop ----
  const int q   = w & 3;
  const int k2  = w >> 2;               // 0..1
  const int bi  = bi0 + q;
  const int mb  = bi << 9;
  const float* fbase = f_ij + ((size_t)mb << 6);
  const float* cb    = c_ij + mb;
  const int na  = na_s[q];
  const int nch = (na + 15) >> 4;
  char* myh = (char*)hT + (w << 12);    // private 4KB: 16 rows x 256B
  const int swj = lrow << 4;            // my j-row swizzle (row = lane&15)

  f32x4 accy[8];
  #pragma unroll
  for (int nt = 0; nt < 8; ++nt) accy[nt] = fzero4();

  for (int c = k2; c < nch; c += 2) {
    const int ridx = (c << 4) + lrow;
    const int ja   = jl[q][ridx];       // 0 for padded tail (valid memory)
    const float sval = (ridx < na) ? cb[ja] * LN2 : 0.f;
    const float* xr = xi + ((size_t)((b << 9) + ja) << 7);

    // ---- f -> B-frags (lane's own j-row) ----
    bf16x8 fb[2];
    #pragma unroll
    for (int ks = 0; ks < 2; ++ks) {
      const float* fp = fbase + ja * 64 + ks * 32 + lgrp * 8;
      f32x4 v0 = *(const f32x4*)fp;
      f32x4 v1 = *(const f32x4*)(fp + 4);
      u32x4 pk = pack8(v0, v1);
      fb[ks] = __builtin_bit_cast(bf16x8, pk);
    }

    f32x4 acc[8];

    // ---- G1: h1[n, j] = Wt0 * f^T (K=64), A streamed from ws0 ----
    #pragma unroll
    for (int nt = 0; nt < 8; ++nt) acc[nt] = fzero4();
    #pragma unroll
    for (int nt = 0; nt < 8; ++nt) {
      const int n = nt * 16 + lrow;
      const char* ap = (const char*)ws0 + n * 128;
      const int sw = (n & 7) << 4;
      #pragma unroll
      for (int ks = 0; ks < 2; ++ks) {
        bf16x8 af = *(const bf16x8*)(ap + ((lgrp * 16 + ks * 64) ^ sw));
        acc[nt] = __builtin_amdgcn_mfma_f32_16x16x32_bf16(af, fb[ks], acc[nt], 0, 0, 0);
      }
    }

    // ---- E1: ssp -> bf16 -> private hT (row = my j = lrow) ----
    {
      char* hr = myh + lrow * 256;
      #pragma unroll
      for (int nt = 0; nt < 8; ++nt) {
        f32x4 bp = *(const f32x4*)(bias_l + nt * 16 + lgrp * 4);
        u32x2 pk = ssp4_pack(acc[nt], bp);
        *(u32x2*)(hr + ((nt * 32 + lgrp * 8) ^ swj)) = pk;
      }
    }

    // ---- G2: h2 = Wt1' * h1'^T (K=128) ----
    {
      bf16x8 hb[4];
      const char* hr = myh + lrow * 256;
      #pragma unroll
      for (int kt = 0; kt < 4; ++kt)
        hb[kt] = *(const bf16x8*)(hr + ((lgrp * 16 + kt * 64) ^ swj));
      #pragma unroll
      for (int nt = 0; nt < 8; ++nt) acc[nt] = fzero4();
      #pragma unroll
      for (int nt = 0; nt < 8; ++nt) {
        const int n = nt * 16 + lrow;
        const char* ap = (const char*)ws1 + n * 256;
        const int sw = (n & 15) << 4;
        #pragma unroll
        for (int kt = 0; kt < 4; ++kt) {
          bf16x8 af = *(const bf16x8*)(ap + ((lgrp * 16 + kt * 64) ^ sw));
          acc[nt] = __builtin_amdgcn_mfma_f32_16x16x32_bf16(af, hb[kt], acc[nt], 0, 0, 0);
        }
      }
    }

    // ---- E2: ssp -> bf16 -> private hT (overwrite; within-wave order) ----
    {
      char* hr = myh + lrow * 256;
      #pragma unroll
      for (int nt = 0; nt < 8; ++nt) {
        f32x4 bp = *(const f32x4*)(bias_l + 128 + nt * 16 + lgrp * 4);
        u32x2 pk = ssp4_pack(acc[nt], bp);
        *(u32x2*)(hr + ((nt * 32 + lgrp * 8) ^ swj)) = pk;
      }
    }

    // ---- G3: h3 = Wt2' * h2'^T (K=128) ----
    {
      bf16x8 hb[4];
      const char* hr = myh + lrow * 256;
      #pragma unroll
      for (int kt = 0; kt < 4; ++kt)
        hb[kt] = *(const bf16x8*)(hr + ((lgrp * 16 + kt * 64) ^ swj));
      #pragma unroll
      for (int nt = 0; nt < 8; ++nt) acc[nt] = fzero4();
      #pragma unroll
      for (int nt = 0; nt < 8; ++nt) {
        const int n = nt * 16 + lrow;
        const char* ap = (const char*)ws2 + n * 256;
        const int sw = (n & 15) << 4;
        #pragma unroll
        for (int kt = 0; kt < 4; ++kt) {
          bf16x8 af = *(const bf16x8*)(ap + ((lgrp * 16 + kt * 64) ^ sw));
          acc[nt] = __builtin_amdgcn_mfma_f32_16x16x32_bf16(af, hb[kt], acc[nt], 0, 0, 0);
        }
      }
    }

    // ---- E3: accy += s * xi[ja, n] * h3' ----
    #pragma unroll
    for (int nt = 0; nt < 8; ++nt) {
      f32x4 bp = *(const f32x4*)(bias_l + 256 + nt * 16 + lgrp * 4);
      f32x4 xv = *(const f32x4*)(xr + nt * 16 + lgrp * 4);
      float h0 = ssp_pre(acc[nt].x, bp.x);
      float h1 = ssp_pre(acc[nt].y, bp.y);
      float h2 = ssp_pre(acc[nt].z, bp.z);
      float h3 = ssp_pre(acc[nt].w, bp.w);
      accy[nt].x += sval * xv.x * h0;
      accy[nt].y += sval * xv.y * h1;
      accy[nt].z += sval * xv.z * h2;
      accy[nt].w += sval * xv.w * h3;
    }
  }

  // ---- reduce over 16 j-lanes ----
  #pragma unroll
  for (int d = 1; d < 16; d <<= 1) {
    #pragma unroll
    for (int nt = 0; nt < 8; ++nt) {
      accy[nt].x += __shfl_xor(accy[nt].x, d, 64);
      accy[nt].y += __shfl_xor(accy[nt].y, d, 64);
      accy[nt].z += __shfl_xor(accy[nt].z, d, 64);
      accy[nt].w += __shfl_xor(accy[nt].w, d, 64);
    }
  }
  __syncthreads();                      // all waves done; hT reusable
  float* yred = (float*)hT;             // [8 waves][128]
  if (lrow == 0) {
    #pragma unroll
    for (int nt = 0; nt < 8; ++nt)
      *(f32x4*)(yred + (w << 7) + nt * 16 + lgrp * 4) = accy[nt];
  }
  __syncthreads();
  {
    const int q2 = tid >> 7, n = tid & 127;   // 512 threads = 4 q's x 128 n
    float s = yred[(q2 << 7) + n] + yred[((4 + q2) << 7) + n];
    y[((bi0 + q2) << 7) + n] = s;
  }
}

// ---------------------------------------------------------------------------
extern "C" void kernel_launch(void* const* d_in, const int* in_sizes, int n_in,
                              void* d_out, int out_size, void* d_ws, size_t ws_size,
                              hipStream_t stream)
{
  const float* x    = (const float*)d_in[0];
  const float* f_ij = (const float*)d_in[1];
  const float* c_ij = (const float*)d_in[2];
  const int*   mask = (const int*)d_in[3];
  const float* W_bc = (const float*)d_in[4];
  const float* b_bc = (const float*)d_in[5];
  const float* A_bc = (const float*)d_in[6];
  const float* B_bc = (const float*)d_in[7];
  const float* W_f0 = (const float*)d_in[8];
  const float* b_f0 = (const float*)d_in[9];
  const float* A_f0 = (const float*)d_in[10];
  const float* B_f0 = (const float*)d_in[11];
  const float* W_f1 = (const float*)d_in[12];
  const float* b_f1 = (const float*)d_in[13];
  const float* A_f1 = (const float*)d_in[14];
  const float* B_f1 = (const float*)d_in[15];
  const float* W_f2 = (const float*)d_in[16];
  const float* b_f2 = (const float*)d_in[17];
  const float* A_f2 = (const float*)d_in[18];
  const float* B_f2 = (const float*)d_in[19];
  const float* W_a0 = (const float*)d_in[20];
  const float* b_a0 = (const float*)d_in[21];
  const float* A_a0 = (const float*)d_in[22];
  const float* B_a0 = (const float*)d_in[23];
  const float* W_a1 = (const float*)d_in[24];
  const float* b_a1 = (const float*)d_in[25];
  const float* A_a1 = (const float*)d_in[26];
  const float* B_a1 = (const float*)d_in[27];
  float* out = (float*)d_out;

  char* ws = (char*)d_ws;
  unsigned short* Wt0 = (unsigned short*)(ws);            //  32768 B
  unsigned short* Wt1 = (unsigned short*)(ws + 32768);    //  65536 B
  unsigned short* Wt2 = (unsigned short*)(ws + 98304);    //  65536 B
  float* Wbc = (float*)(ws + 163840);                     // 131072 B
  float* Wa0 = (float*)(ws + 294912);                     // 131072 B
  float* Wa1 = (float*)(ws + 425984);                     // 131072 B
  float* xi  = (float*)(ws + 557056);                     // 524288 B
  float* yp  = (float*)(ws + 1081344);                    // 524288 B (~1.6 MB total)

  prep_weights<<<dim3(64, 6, 2), 256, 0, stream>>>(
      W_bc, A_bc, B_bc, W_f0, A_f0, B_f0, W_f1, A_f1, B_f1,
      W_f2, A_f2, B_f2, W_a0, A_a0, B_a0, W_a1, A_a1, B_a1,
      Wt0, Wt1, Wt2, Wbc, Wa0, Wa1);

  dense_ssp<<<256, 512, 0, stream>>>(x, Wbc, b_bc, xi);

  schnet_core<<<256, 512, 0, stream>>>(f_ij, c_ij, mask, Wt0, Wt1, Wt2,
                                       b_f0, b_f1, b_f2, xi, yp);

  dense2_ssp<<<256, 512, 0, stream>>>(yp, Wa0, b_a0, Wa1, b_a1, x, out);
}

// Round 14
// 97.532 us; speedup vs baseline: 5.3977x; 3.7517x over previous
//
#include <hip/hip_runtime.h>
#include <hip/hip_bf16.h>

// LoRAModulatedSchnetInteraction: B=2, A=512, F=128, Rbf=64, R=4
// Strategy:
//  - Fold LoRA into per-batch effective weights: Weff[b] = W + A[b]@B[b]  (prep_weights)
//  - x_i: exact fp32 VALU dense (dense_ssp); final two atomwise layers fused (dense2_ssp)
//  - Core: per-(b,i) block: compact active j (mask), 3-layer bf16-MFMA MLP on f_ij rows,
//    * c_ij * x_i[j,:], masked sum over j -> y  (schnet_core)
//  - R14: REVERT to R6, the empirical optimum (97.1us total, 88.6us core).
//    Falsified since: cross-phase reg prefetch (R7 spill), convoy stagger (R8 null),
//    forced occupancy (R9 spill / R10 per-SIMD reg pool caps at 16 waves /
//    R11 VGPR-36 still 43%), barrier-free wave-solo (R12/R13 scratch-bound,
//    365-526us). R6 config: uniform one-generation grid (1024 blocks, 4/CU),
//    64-row tiles + 16-row pruning, ssp log2-folding (ln2 into Wt1/Wt2/slist,
//    0.5 into bias), fbuf 8-slot / hbuf 16-slot swizzles, 4 barriers/tile,
//    staged in-loop weight reloads, guarded f-tile reg prefetch, VGPR 64.

typedef float        f32x4  __attribute__((ext_vector_type(4)));
typedef unsigned int u32x4  __attribute__((ext_vector_type(4)));
typedef unsigned int u32x2  __attribute__((ext_vector_type(2)));
typedef __bf16       bf16x8 __attribute__((ext_vector_type(8)));

#define LOG2E 1.44269504089f
#define LN2   0.69314718056f

// h' = ssp(acc+b)/ln2 = log2(2^(acc*log2e + b*log2e - 1) + 0.5)
// bpre = b*log2e - 1. Consumers absorb the ln2 (next-layer weights / slist).
__device__ __forceinline__ float ssp_pre(float acc, float bpre) {
  float t = __builtin_amdgcn_exp2f(__builtin_fmaf(acc, LOG2E, bpre));
  return __builtin_amdgcn_logf(t + 0.5f);
}

__device__ __forceinline__ float ssp_f(float v) {
  float t = __builtin_amdgcn_exp2f(v * LOG2E);
  return LN2 * __builtin_amdgcn_logf(__builtin_fmaf(t, 0.5f, 0.5f));
}

__device__ __forceinline__ unsigned short f2bfu(float f) {
  __hip_bfloat16 h = __float2bfloat16(f);
  return __builtin_bit_cast(unsigned short, h);
}

__device__ __forceinline__ u32x4 pack8(f32x4 a, f32x4 b) {
  u32x4 u;
  u.x = (unsigned)f2bfu(a.x) | ((unsigned)f2bfu(a.y) << 16);
  u.y = (unsigned)f2bfu(a.z) | ((unsigned)f2bfu(a.w) << 16);
  u.z = (unsigned)f2bfu(b.x) | ((unsigned)f2bfu(b.y) << 16);
  u.w = (unsigned)f2bfu(b.z) | ((unsigned)f2bfu(b.w) << 16);
  return u;
}

__device__ __forceinline__ f32x4 fzero4() { f32x4 z = {0.f, 0.f, 0.f, 0.f}; return z; }

#define SWZF(j) (((j) & 7) << 4)     // fbuf: 128B rows, 8 slots
#define SWZH(j) (((j) & 15) << 4)    // hbuf: 256B rows, 16 slots

// ---------------------------------------------------------------------------
// Weight prep: Weff[b] = W + A[b] @ B[b].
// Filter layers (l=1,2,3) stored TRANSPOSED bf16 [b][nout][din]; l=2,3 pre-scaled
// by ln2 (ssp log2-form folding). bc/a0/a1 stored fp32 [b][k][n].
// ---------------------------------------------------------------------------
__global__ void prep_weights(
    const float* __restrict__ W_bc, const float* __restrict__ A_bc, const float* __restrict__ B_bc,
    const float* __restrict__ W_f0, const float* __restrict__ A_f0, const float* __restrict__ B_f0,
    const float* __restrict__ W_f1, const float* __restrict__ A_f1, const float* __restrict__ B_f1,
    const float* __restrict__ W_f2, const float* __restrict__ A_f2, const float* __restrict__ B_f2,
    const float* __restrict__ W_a0, const float* __restrict__ A_a0, const float* __restrict__ B_a0,
    const float* __restrict__ W_a1, const float* __restrict__ A_a1, const float* __restrict__ B_a1,
    unsigned short* __restrict__ Wt0, unsigned short* __restrict__ Wt1, unsigned short* __restrict__ Wt2,
    float* __restrict__ Wbc, float* __restrict__ Wa0, float* __restrict__ Wa1)
{
  const int l = blockIdx.y, b = blockIdx.z;
  const int e = blockIdx.x * 256 + threadIdx.x;
  const float *W, *A, *Bm; int din;
  switch (l) {
    case 0:  W = W_bc; A = A_bc; Bm = B_bc; din = 128; break;
    case 1:  W = W_f0; A = A_f0; Bm = B_f0; din = 64;  break;
    case 2:  W = W_f1; A = A_f1; Bm = B_f1; din = 128; break;
    case 3:  W = W_f2; A = A_f2; Bm = B_f2; din = 128; break;
    case 4:  W = W_a0; A = A_a0; Bm = B_a0; din = 128; break;
    default: W = W_a1; A = A_a1; Bm = B_a1; din = 128; break;
  }
  if (e >= din * 128) return;
  const int k = e >> 7, n = e & 127;
  float wv = W[k * 128 + n];
  #pragma unroll
  for (int r = 0; r < 4; ++r)
    wv += A[(b * din + k) * 4 + r] * Bm[(b * 4 + r) * 128 + n];
  if (l == 1)      Wt0[(b * 128 + n) * 64  + k] = f2bfu(wv);
  else if (l == 2) Wt1[(b * 128 + n) * 128 + k] = f2bfu(wv * LN2);
  else if (l == 3) Wt2[(b * 128 + n) * 128 + k] = f2bfu(wv * LN2);
  else if (l == 0) Wbc[(b * 128 + k) * 128 + n] = wv;
  else if (l == 4) Wa0[(b * 128 + k) * 128 + n] = wv;
  else             Wa1[(b * 128 + k) * 128 + n] = wv;
}

// ---------------------------------------------------------------------------
// dense_ssp: out[row,n] = ssp(sum_k in[row,k]*W[b,k,n] + bias[n])
// ---------------------------------------------------------------------------
__global__ __launch_bounds__(512) void dense_ssp(
    const float* __restrict__ in, const float* __restrict__ W,
    const float* __restrict__ bias, float* __restrict__ out)
{
  __shared__ float in_l[4][128];
  const int t = threadIdx.x;
  const int rg0 = blockIdx.x << 2;
  const int b = rg0 >> 9;
  in_l[t >> 7][t & 127] = in[rg0 * 128 + t];
  __syncthreads();
  const int j = t >> 7, n = t & 127;
  const float* wp = W + (b << 14) + n;
  const float* ip = in_l[j];
  float acc = 0.f;
  #pragma unroll 8
  for (int k = 0; k < 128; ++k) acc += ip[k] * wp[k << 7];
  out[(rg0 + j) * 128 + n] = ssp_f(acc + bias[n]);
}

// ---------------------------------------------------------------------------
// dense2_ssp: fused final two atomwise layers.
// h = ssp(in @ W0 + b0); out = ssp(h @ W1 + b1) + resid
// ---------------------------------------------------------------------------
__global__ __launch_bounds__(512) void dense2_ssp(
    const float* __restrict__ in,
    const float* __restrict__ W0, const float* __restrict__ b0,
    const float* __restrict__ W1, const float* __restrict__ b1,
    const float* __restrict__ resid, float* __restrict__ out)
{
  __shared__ float in_l[4][128];
  __shared__ float h_l[4][128];
  const int t = threadIdx.x;
  const int rg0 = blockIdx.x << 2;
  const int b = rg0 >> 9;
  in_l[t >> 7][t & 127] = in[rg0 * 128 + t];
  __syncthreads();
  const int j = t >> 7, n = t & 127;
  {
    const float* wp = W0 + (b << 14) + n;
    const float* ip = in_l[j];
    float acc = 0.f;
    #pragma unroll 8
    for (int k = 0; k < 128; ++k) acc += ip[k] * wp[k << 7];
    h_l[j][n] = ssp_f(acc + b0[n]);
  }
  __syncthreads();
  {
    const float* wp = W1 + (b << 14) + n;
    const float* ip = h_l[j];
    float acc = 0.f;
    #pragma unroll 8
    for (int k = 0; k < 128; ++k) acc += ip[k] * wp[k << 7];
    const int oi = (rg0 + j) * 128 + n;
    out[oi] = ssp_f(acc + b1[n]) + resid[oi];
  }
}

// ---------------------------------------------------------------------------
// schnet_core: grid 1024 = b*512+i (one generation: 4 blocks/CU resident).
// 256 threads = 4 waves; wave w owns nout [w*32, w*32+32).
// Compacts all 512 j's; tiles of 64 rows, 16-row sub-tile pruning via uniform
// guards (jt*16 < na-jt0) with static unroll.
// Per tile: S pack->fbuf | B1 | next-f prefetch | G1(wfA) | issue wfB | E1->h |
//   B2 | G2(wfB) | B2' | issue wfC | E2->h | B3 | G3(wfC) | issue wfA' | E3.
// ---------------------------------------------------------------------------
__global__ __launch_bounds__(256, 4) void schnet_core(
    const float* __restrict__ f_ij, const float* __restrict__ c_ij,
    const int* __restrict__ mask,
    const unsigned short* __restrict__ Wt0, const unsigned short* __restrict__ Wt1,
    const unsigned short* __restrict__ Wt2,
    const float* __restrict__ bias0, const float* __restrict__ bias1,
    const float* __restrict__ bias2,
    const float* __restrict__ xi, float* __restrict__ y)
{
  __shared__ __align__(16) unsigned short fbuf[64 * 64];    // [j][k] bf16, 8-slot swz
  __shared__ __align__(16) unsigned short hbuf[64 * 128];   // h', 16-slot swz
  __shared__ int   jlist[576];
  __shared__ float slist[576];
  __shared__ float bias_l[384];          // 3x128: b*log2e - 1
  __shared__ int cnt_s[8], base_s[8], nact_s;

  const int tid  = threadIdx.x;
  const int lane = tid & 63;
  const int w    = tid >> 6;
  const int lrow = lane & 15;
  const int lgrp = lane >> 4;
  const int bi   = blockIdx.x;          // b*512 + i
  const int b    = bi >> 9;

  // ---- bias staging: pre-scaled so t = fma(acc, log2e, bpre); 0.5 folded ----
  for (int t = tid; t < 384; t += 256) {
    const float* bp = (t < 128) ? bias0 : (t < 256) ? bias1 : bias2;
    bias_l[t] = __builtin_fmaf(bp[t & 127], LOG2E, -1.0f);
  }

  // ---- deterministic compaction of all 512 j's (slist pre-scaled by ln2) ----
  const int mb = bi << 9;
  const int jA = tid, jB = tid + 256;
  const int   mA = mask[mb + jA]; const float cA = c_ij[mb + jA];
  const int   mB = mask[mb + jB]; const float cB = c_ij[mb + jB];
  unsigned long long balA = __ballot(mA != 0);
  unsigned long long balB = __ballot(mB != 0);
  if (lane == 0) { cnt_s[w] = __popcll(balA); cnt_s[4 + w] = __popcll(balB); }
  __syncthreads();
  if (tid == 0) {
    int s = 0;
    for (int c = 0; c < 8; ++c) { base_s[c] = s; s += cnt_s[c]; }
    nact_s = s;
  }
  __syncthreads();
  const int na = nact_s;
  const unsigned long long lm = (1ull << lane) - 1ull;
  if (mA) { int p = base_s[w]     + __popcll(balA & lm); jlist[p] = jA; slist[p] = cA * LN2; }
  if (mB) { int p = base_s[4 + w] + __popcll(balB & lm); jlist[p] = jB; slist[p] = cB * LN2; }
  if (tid < 64) { int idx = na + tid; if (idx < 576) { jlist[idx] = 0; slist[idx] = 0.f; } }
  __syncthreads();

  const int tiles = (na + 63) >> 6;

  const int mg = w;
  const float* fbase = f_ij + ((size_t)mb << 6);

  const int wbase0 = ((b << 7) + mg * 32 + lrow) * 64  + (lgrp << 3);
  const int wbase1 = ((b << 7) + mg * 32 + lrow) * 128 + (lgrp << 3);

  float accy[2][4] = {{0.f,0.f,0.f,0.f},{0.f,0.f,0.f,0.f}};

  // ---- initial wfA (G1 weights) ----
  bf16x8 wfA[2][2];
  {
    const unsigned short* wp = Wt0 + wbase0;
    #pragma unroll
    for (int nt = 0; nt < 2; ++nt)
      #pragma unroll
      for (int ks = 0; ks < 2; ++ks)
        wfA[nt][ks] = *(const bf16x8*)(wp + nt * (16 * 64) + ks * 32);
  }

  // ---- prefetch first f tile into regs ----
  const int r    = tid >> 2;
  const int part = tid & 3;
  f32x4 pre0, pre1, pre2, pre3;
  {
    const int ja = jlist[r];
    const f32x4* src = (const f32x4*)(fbase + ja * 64 + part * 16);
    pre0 = src[0]; pre1 = src[1]; pre2 = src[2]; pre3 = src[3];
  }

  for (int tt = 0; tt < tiles; ++tt) {
    const int jt0 = tt << 6;
    const int jcnt = na - jt0;          // rows remaining (uniform)

    // ---- S: pack prefetched regs -> fbuf ----
    {
      char* dst = (char*)fbuf + r * 128;
      const int o0 = (part * 32) ^ SWZF(r);
      *(u32x4*)(dst + o0)        = pack8(pre0, pre1);
      *(u32x4*)(dst + (o0 ^ 16)) = pack8(pre2, pre3);
    }
    __syncthreads();                    // B1: fbuf ready

    // ---- guarded next-f prefetch ----
    if (tt + 1 < tiles) {
      const int ja = jlist[((tt + 1) << 6) + r];
      const f32x4* src = (const f32x4*)(fbase + ja * 64 + part * 16);
      pre0 = src[0]; pre1 = src[1]; pre2 = src[2]; pre3 = src[3];
    }

    f32x4 acc[2][4];

    // ---- G1: h1^T = Wt0 * f^T (K=64) ----
    #pragma unroll
    for (int nt = 0; nt < 2; ++nt)
      #pragma unroll
      for (int jt = 0; jt < 4; ++jt) acc[nt][jt] = fzero4();
    #pragma unroll
    for (int jt = 0; jt < 4; ++jt) {
      if (jt * 16 < jcnt) {
        const int j = jt * 16 + lrow;
        const char* rb = (const char*)fbuf + j * 128;
        const int sw = SWZF(j);
        #pragma unroll
        for (int ks = 0; ks < 2; ++ks) {
          bf16x8 bf = *(const bf16x8*)(rb + ((lgrp * 16 + ks * 64) ^ sw));
          acc[0][jt] = __builtin_amdgcn_mfma_f32_16x16x32_bf16(wfA[0][ks], bf, acc[0][jt], 0, 0, 0);
          acc[1][jt] = __builtin_amdgcn_mfma_f32_16x16x32_bf16(wfA[1][ks], bf, acc[1][jt], 0, 0, 0);
        }
      }
    }

    // ---- issue wfB (G2 weights) ----
    bf16x8 wfB[2][4];
    {
      const unsigned short* wp = Wt1 + wbase1;
      asm volatile("" : "+v"(wp));
      #pragma unroll
      for (int nt = 0; nt < 2; ++nt)
        #pragma unroll
        for (int ks = 0; ks < 4; ++ks)
          wfB[nt][ks] = *(const bf16x8*)(wp + nt * (16 * 128) + ks * 32);
    }

    // ---- E1: h1' -> bf16 -> hbuf ----
    {
      f32x4 bp0 = *(const f32x4*)(bias_l + mg * 32 + 0  + lgrp * 4);
      f32x4 bp1 = *(const f32x4*)(bias_l + mg * 32 + 16 + lgrp * 4);
      #pragma unroll
      for (int jt = 0; jt < 4; ++jt) {
        if (jt * 16 < jcnt) {
          const int j = jt * 16 + lrow;
          char* rb = (char*)hbuf + j * 256;
          const int sw = SWZH(j);
          #pragma unroll
          for (int nt = 0; nt < 2; ++nt) {
            const int n0 = mg * 32 + nt * 16 + lgrp * 4;
            const f32x4 bp = nt ? bp1 : bp0;
            float e0 = ssp_pre(acc[nt][jt].x, bp.x);
            float e1 = ssp_pre(acc[nt][jt].y, bp.y);
            float e2 = ssp_pre(acc[nt][jt].z, bp.z);
            float e3 = ssp_pre(acc[nt][jt].w, bp.w);
            u32x2 pk;
            pk.x = (unsigned)f2bfu(e0) | ((unsigned)f2bfu(e1) << 16);
            pk.y = (unsigned)f2bfu(e2) | ((unsigned)f2bfu(e3) << 16);
            *(u32x2*)(rb + ((n0 * 2) ^ sw)) = pk;
          }
        }
      }
    }
    __syncthreads();                    // B2: h1 ready

    // ---- G2: h2^T = Wt1' * h1'^T (K=128) ----
    #pragma unroll
    for (int nt = 0; nt < 2; ++nt)
      #pragma unroll
      for (int jt = 0; jt < 4; ++jt) acc[nt][jt] = fzero4();
    #pragma unroll
    for (int jt = 0; jt < 4; ++jt) {
      if (jt * 16 < jcnt) {
        const int j = jt * 16 + lrow;
        const char* rb = (const char*)hbuf + j * 256;
        const int sw = SWZH(j);
        #pragma unroll
        for (int ks = 0; ks < 4; ++ks) {
          bf16x8 bf = *(const bf16x8*)(rb + ((lgrp * 16 + ks * 64) ^ sw));
          acc[0][jt] = __builtin_amdgcn_mfma_f32_16x16x32_bf16(wfB[0][ks], bf, acc[0][jt], 0, 0, 0);
          acc[1][jt] = __builtin_amdgcn_mfma_f32_16x16x32_bf16(wfB[1][ks], bf, acc[1][jt], 0, 0, 0);
        }
      }
    }
    __syncthreads();                    // B2': h1 readers done

    // ---- issue wfC (G3 weights) ----
    bf16x8 wfC[2][4];
    {
      const unsigned short* wp = Wt2 + wbase1;
      asm volatile("" : "+v"(wp));
      #pragma unroll
      for (int nt = 0; nt < 2; ++nt)
        #pragma unroll
        for (int ks = 0; ks < 4; ++ks)
          wfC[nt][ks] = *(const bf16x8*)(wp + nt * (16 * 128) + ks * 32);
    }

    // ---- E2: h2' -> bf16 -> hbuf ----
    {
      f32x4 bp0 = *(const f32x4*)(bias_l + 128 + mg * 32 + 0  + lgrp * 4);
      f32x4 bp1 = *(const f32x4*)(bias_l + 128 + mg * 32 + 16 + lgrp * 4);
      #pragma unroll
      for (int jt = 0; jt < 4; ++jt) {
        if (jt * 16 < jcnt) {
          const int j = jt * 16 + lrow;
          char* rb = (char*)hbuf + j * 256;
          const int sw = SWZH(j);
          #pragma unroll
          for (int nt = 0; nt < 2; ++nt) {
            const int n0 = mg * 32 + nt * 16 + lgrp * 4;
            const f32x4 bp = nt ? bp1 : bp0;
            float e0 = ssp_pre(acc[nt][jt].x, bp.x);
            float e1 = ssp_pre(acc[nt][jt].y, bp.y);
            float e2 = ssp_pre(acc[nt][jt].z, bp.z);
            float e3 = ssp_pre(acc[nt][jt].w, bp.w);
            u32x2 pk;
            pk.x = (unsigned)f2bfu(e0) | ((unsigned)f2bfu(e1) << 16);
            pk.y = (unsigned)f2bfu(e2) | ((unsigned)f2bfu(e3) << 16);
            *(u32x2*)(rb + ((n0 * 2) ^ sw)) = pk;
          }
        }
      }
    }
    __syncthreads();                    // B3: h2 ready

    // ---- G3: h3^T = Wt2' * h2'^T (K=128) ----
    #pragma unroll
    for (int nt = 0; nt < 2; ++nt)
      #pragma unroll
      for (int jt = 0; jt < 4; ++jt) acc[nt][jt] = fzero4();
    #pragma unroll
    for (int jt = 0; jt < 4; ++jt) {
      if (jt * 16 < jcnt) {
        const int j = jt * 16 + lrow;
        const char* rb = (const char*)hbuf + j * 256;
        const int sw = SWZH(j);
        #pragma unroll
        for (int ks = 0; ks < 4; ++ks) {
          bf16x8 bf = *(const bf16x8*)(rb + ((lgrp * 16 + ks * 64) ^ sw));
          acc[0][jt] = __builtin_amdgcn_mfma_f32_16x16x32_bf16(wfC[0][ks], bf, acc[0][jt], 0, 0, 0);
          acc[1][jt] = __builtin_amdgcn_mfma_f32_16x16x32_bf16(wfC[1][ks], bf, acc[1][jt], 0, 0, 0);
        }
      }
    }

    // ---- issue wfA' (next tile's G1 weights) ----
    {
      const unsigned short* wp = Wt0 + wbase0;
      asm volatile("" : "+v"(wp));
      #pragma unroll
      for (int nt = 0; nt < 2; ++nt)
        #pragma unroll
        for (int ks = 0; ks < 2; ++ks)
          wfA[nt][ks] = *(const bf16x8*)(wp + nt * (16 * 64) + ks * 32);
    }

    // ---- E3: h3' = log2-form; accy += (s*ln2) * xi[j,f] * h3' ----
    {
      f32x4 bp0 = *(const f32x4*)(bias_l + 256 + mg * 32 + 0  + lgrp * 4);
      f32x4 bp1 = *(const f32x4*)(bias_l + 256 + mg * 32 + 16 + lgrp * 4);
      #pragma unroll
      for (int jt = 0; jt < 4; ++jt) {
        if (jt * 16 < jcnt) {
          const int jj = jt * 16 + lrow;
          const float s  = slist[jt0 + jj];
          const int   ja = jlist[jt0 + jj];
          const float* xr = xi + (((b << 9) + ja) << 7);
          #pragma unroll
          for (int nt = 0; nt < 2; ++nt) {
            const int n0 = mg * 32 + nt * 16 + lgrp * 4;
            const f32x4 bp = nt ? bp1 : bp0;
            f32x4 xv = *(const f32x4*)(xr + n0);
            float h0 = ssp_pre(acc[nt][jt].x, bp.x);
            float h1 = ssp_pre(acc[nt][jt].y, bp.y);
            float h2 = ssp_pre(acc[nt][jt].z, bp.z);
            float h3 = ssp_pre(acc[nt][jt].w, bp.w);
            accy[nt][0] += s * xv.x * h0;
            accy[nt][1] += s * xv.y * h1;
            accy[nt][2] += s * xv.z * h2;
            accy[nt][3] += s * xv.w * h3;
          }
        }
      }
    }
    // no loop-end barrier: B1(t+1) orders G3/E3 reads vs next writes
  }

  // ---- reduce over the 16 j-sub-lanes; write y[b,i,:] ----
  #pragma unroll
  for (int d = 1; d < 16; d <<= 1)
    #pragma unroll
    for (int nt = 0; nt < 2; ++nt)
      #pragma unroll
      for (int rr = 0; rr < 4; ++rr)
        accy[nt][rr] += __shfl_xor(accy[nt][rr], d, 64);
  if (lrow == 0) {
    float* yo = y + ((size_t)bi << 7);
    #pragma unroll
    for (int nt = 0; nt < 2; ++nt) {
      const int n0 = mg * 32 + nt * 16 + lgrp * 4;
      f32x4 v = {accy[nt][0], accy[nt][1], accy[nt][2], accy[nt][3]};
      *(f32x4*)(yo + n0) = v;
    }
  }
}

// ---------------------------------------------------------------------------
extern "C" void kernel_launch(void* const* d_in, const int* in_sizes, int n_in,
                              void* d_out, int out_size, void* d_ws, size_t ws_size,
                              hipStream_t stream)
{
  const float* x    = (const float*)d_in[0];
  const float* f_ij = (const float*)d_in[1];
  const float* c_ij = (const float*)d_in[2];
  const int*   mask = (const int*)d_in[3];
  const float* W_bc = (const float*)d_in[4];
  const float* b_bc = (const float*)d_in[5];
  const float* A_bc = (const float*)d_in[6];
  const float* B_bc = (const float*)d_in[7];
  const float* W_f0 = (const float*)d_in[8];
  const float* b_f0 = (const float*)d_in[9];
  const float* A_f0 = (const float*)d_in[10];
  const float* B_f0 = (const float*)d_in[11];
  const float* W_f1 = (const float*)d_in[12];
  const float* b_f1 = (const float*)d_in[13];
  const float* A_f1 = (const float*)d_in[14];
  const float* B_f1 = (const float*)d_in[15];
  const float* W_f2 = (const float*)d_in[16];
  const float* b_f2 = (const float*)d_in[17];
  const float* A_f2 = (const float*)d_in[18];
  const float* B_f2 = (const float*)d_in[19];
  const float* W_a0 = (const float*)d_in[20];
  const float* b_a0 = (const float*)d_in[21];
  const float* A_a0 = (const float*)d_in[22];
  const float* B_a0 = (const float*)d_in[23];
  const float* W_a1 = (const float*)d_in[24];
  const float* b_a1 = (const float*)d_in[25];
  const float* A_a1 = (const float*)d_in[26];
  const float* B_a1 = (const float*)d_in[27];
  float* out = (float*)d_out;

  char* ws = (char*)d_ws;
  unsigned short* Wt0 = (unsigned short*)(ws);            //  32768 B
  unsigned short* Wt1 = (unsigned short*)(ws + 32768);    //  65536 B
  unsigned short* Wt2 = (unsigned short*)(ws + 98304);    //  65536 B
  float* Wbc = (float*)(ws + 163840);                     // 131072 B
  float* Wa0 = (float*)(ws + 294912);                     // 131072 B
  float* Wa1 = (float*)(ws + 425984);                     // 131072 B
  float* xi  = (float*)(ws + 557056);                     // 524288 B
  float* yp  = (float*)(ws + 1081344);                    // 524288 B (~1.6 MB total)

  prep_weights<<<dim3(64, 6, 2), 256, 0, stream>>>(
      W_bc, A_bc, B_bc, W_f0, A_f0, B_f0, W_f1, A_f1, B_f1,
      W_f2, A_f2, B_f2, W_a0, A_a0, B_a0, W_a1, A_a1, B_a1,
      Wt0, Wt1, Wt2, Wbc, Wa0, Wa1);

  dense_ssp<<<256, 512, 0, stream>>>(x, Wbc, b_bc, xi);

  schnet_core<<<1024, 256, 0, stream>>>(f_ij, c_ij, mask, Wt0, Wt1, Wt2,
                                        b_f0, b_f1, b_f2, xi, yp);

  dense2_ssp<<<256, 512, 0, stream>>>(yp, Wa0, b_a0, Wa1, b_a1, x, out);
}